// Round 1
// baseline (274.598 us; speedup 1.0000x reference)
//
#include <hip/hip_runtime.h>

typedef __attribute__((ext_vector_type(8))) short bf16x8;
typedef __attribute__((ext_vector_type(4))) float f32x4;

#define MFMA_BF16(A, B, C) __builtin_amdgcn_mfma_f32_16x16x32_bf16((A), (B), (C), 0, 0, 0)

static __device__ __forceinline__ unsigned short f32_to_bf16(float f) {
    unsigned int u = __builtin_bit_cast(unsigned int, f);
    u += 0x7fffu + ((u >> 16) & 1u);
    return (unsigned short)(u >> 16);
}

// ---------------------------------------------------------------- cast f32 -> bf16
__global__ void cast_f32_bf16(const float* __restrict__ in, unsigned short* __restrict__ out, int n4) {
    int i = blockIdx.x * 256 + threadIdx.x;
    if (i >= n4) return;
    float4 v = reinterpret_cast<const float4*>(in)[i];
    ushort4 o;
    o.x = f32_to_bf16(v.x);
    o.y = f32_to_bf16(v.y);
    o.z = f32_to_bf16(v.z);
    o.w = f32_to_bf16(v.w);
    reinterpret_cast<ushort4*>(out)[i] = o;
}

// ---------------------------------------------------------------- GEMM  C = A[M,K] * B[N,K]^T
// MODE 0: QKV projection epilogue (scatter to q/k/v [b,h,s,64] bf16, scale q by 0.125)
// MODE 1: out projection epilogue (fp32 to d_out [M,N])
template <int MODE>
__global__ __launch_bounds__(256, 2)
void gemm_bt(const unsigned short* __restrict__ Ag,
             const unsigned short* __restrict__ Bg,
             int N, int K,
             unsigned short* __restrict__ qO,
             unsigned short* __restrict__ kO,
             unsigned short* __restrict__ vO,
             float* __restrict__ fO)
{
    constexpr int BM = 128, BN = 128, BK = 64;
    __shared__ unsigned short sA[BM * BK];
    __shared__ unsigned short sB[BN * BK];

    const int m0 = blockIdx.y * BM;
    const int n0 = blockIdx.x * BN;
    const int t = threadIdx.x;
    const int lane = t & 63;
    const int wid = t >> 6;
    const int wr = wid >> 1, wc = wid & 1;   // 2x2 wave grid, 64x64 per wave
    const int g = lane >> 4, r = lane & 15;

    const f32x4 fzero = {0.f, 0.f, 0.f, 0.f};
    f32x4 acc[4][4];
#pragma unroll
    for (int mi = 0; mi < 4; ++mi)
#pragma unroll
        for (int ni = 0; ni < 4; ++ni) acc[mi][ni] = fzero;

    const int srow = t >> 3;   // 0..31
    const int schunk = t & 7;  // 0..7  (8-elem = 16B chunks)

    for (int k0 = 0; k0 < K; k0 += BK) {
        __syncthreads();
#pragma unroll
        for (int rep = 0; rep < 4; ++rep) {
            const int row = srow + rep * 32;
            const int soff = row * BK + ((schunk * 8) ^ ((row & 7) * 8));  // XOR swizzle, 16B granules
            *reinterpret_cast<bf16x8*>(&sA[soff]) =
                *reinterpret_cast<const bf16x8*>(&Ag[(size_t)(m0 + row) * K + k0 + schunk * 8]);
            *reinterpret_cast<bf16x8*>(&sB[soff]) =
                *reinterpret_cast<const bf16x8*>(&Bg[(size_t)(n0 + row) * K + k0 + schunk * 8]);
        }
        __syncthreads();

#pragma unroll
        for (int ks = 0; ks < BK; ks += 32) {
            const int c = (ks >> 3) + g;
            bf16x8 af[4], bfr[4];
#pragma unroll
            for (int mi = 0; mi < 4; ++mi) {
                const int row = wr * 64 + mi * 16 + r;
                af[mi] = *reinterpret_cast<const bf16x8*>(&sA[row * BK + ((c * 8) ^ ((row & 7) * 8))]);
            }
#pragma unroll
            for (int ni = 0; ni < 4; ++ni) {
                const int row = wc * 64 + ni * 16 + r;
                bfr[ni] = *reinterpret_cast<const bf16x8*>(&sB[row * BK + ((c * 8) ^ ((row & 7) * 8))]);
            }
#pragma unroll
            for (int mi = 0; mi < 4; ++mi)
#pragma unroll
                for (int ni = 0; ni < 4; ++ni)
                    acc[mi][ni] = MFMA_BF16(af[mi], bfr[ni], acc[mi][ni]);
        }
    }

    // Epilogue. D layout: row = 4*g + i, col = r (within each 16x16 fragment).
#pragma unroll
    for (int mi = 0; mi < 4; ++mi) {
#pragma unroll
        for (int ni = 0; ni < 4; ++ni) {
            const int mbase = m0 + wr * 64 + mi * 16 + 4 * g;
            const int n = n0 + wc * 64 + ni * 16 + r;
#pragma unroll
            for (int i = 0; i < 4; ++i) {
                const int m = mbase + i;
                const float val = acc[mi][ni][i];
                if (MODE == 0) {
                    const int b = m >> 11, s = m & 2047;
                    const int which = n >> 10;       // 0=q 1=k 2=v
                    const int h = (n >> 6) & 15;
                    const int d = n & 63;
                    const size_t dst = (((size_t)(b * 16 + h)) * 2048 + s) * 64 + d;
                    if (which == 0)      qO[dst] = f32_to_bf16(val * 0.125f);  // fold softmax scale (exact)
                    else if (which == 1) kO[dst] = f32_to_bf16(val);
                    else                 vO[dst] = f32_to_bf16(val);
                } else {
                    fO[(size_t)m * N + n] = val;
                }
            }
        }
    }
}

// ---------------------------------------------------------------- flash attention
// grid: 32 heads * 32 qblocks. Block = 4 waves; each wave owns 16 q-rows. 32-key steps.
__global__ __launch_bounds__(256, 2)
void attn_kernel(const unsigned short* __restrict__ Q,
                 const unsigned short* __restrict__ Kt,
                 const unsigned short* __restrict__ Vt,
                 unsigned short* __restrict__ ctx)
{
    const int S = 2048;
    const int hb = blockIdx.x >> 5;   // b*16+h
    const int qb = blockIdx.x & 31;
    const unsigned short* Qh = Q + (size_t)hb * S * 64;
    const unsigned short* Kh = Kt + (size_t)hb * S * 64;
    const unsigned short* Vh = Vt + (size_t)hb * S * 64;

    const int t = threadIdx.x;
    const int lane = t & 63, wid = t >> 6;
    const int g = lane >> 4, r = lane & 15;
    const int q0 = qb * 64 + wid * 16;

    __shared__ unsigned short sK[32 * 64];
    __shared__ unsigned short sV[32 * 64];
    __shared__ unsigned short pbuf[4][16 * 40];   // per-wave P transpose buffer (pitch 40 = 80B, 16B aligned)

    // Q fragments (held in registers for whole kernel); q already scaled by 1/8
    bf16x8 qf[2];
#pragma unroll
    for (int h = 0; h < 2; ++h)
        qf[h] = *reinterpret_cast<const bf16x8*>(&Qh[(size_t)(q0 + r) * 64 + h * 32 + g * 8]);

    const f32x4 fzero = {0.f, 0.f, 0.f, 0.f};
    f32x4 acc[4];
#pragma unroll
    for (int dt = 0; dt < 4; ++dt) acc[dt] = fzero;
    float mrun[4], lrun[4];
#pragma unroll
    for (int i = 0; i < 4; ++i) { mrun[i] = -1e30f; lrun[i] = 0.f; }

    const int srow = t >> 3, schunk = t & 7;

    for (int k0 = 0; k0 < S; k0 += 32) {
        __syncthreads();
        {   // cooperative stage of K,V 32x64 tiles (one 16B chunk per thread per matrix)
            const int soff = srow * 64 + ((schunk * 8) ^ ((srow & 7) * 8));
            *reinterpret_cast<bf16x8*>(&sK[soff]) =
                *reinterpret_cast<const bf16x8*>(&Kh[(size_t)(k0 + srow) * 64 + schunk * 8]);
            *reinterpret_cast<bf16x8*>(&sV[soff]) =
                *reinterpret_cast<const bf16x8*>(&Vh[(size_t)(k0 + srow) * 64 + schunk * 8]);
        }
        __syncthreads();

        // S = Q*K^T : two 16x16 tiles (keys k0..k0+15, k0+16..k0+31)
        f32x4 s0 = fzero, s1 = fzero;
#pragma unroll
        for (int h = 0; h < 2; ++h) {
            const int c = h * 4 + g;
            const int row0 = r, row1 = 16 + r;
            bf16x8 kb0 = *reinterpret_cast<const bf16x8*>(&sK[row0 * 64 + ((c * 8) ^ ((row0 & 7) * 8))]);
            bf16x8 kb1 = *reinterpret_cast<const bf16x8*>(&sK[row1 * 64 + ((c * 8) ^ ((row1 & 7) * 8))]);
            s0 = MFMA_BF16(qf[h], kb0, s0);
            s1 = MFMA_BF16(qf[h], kb1, s1);
        }

        // online softmax; lane holds rows q=4g+i, cols r / 16+r
        float mx[4], p0[4], p1[4], rs[4];
#pragma unroll
        for (int i = 0; i < 4; ++i) mx[i] = fmaxf(s0[i], s1[i]);
#pragma unroll
        for (int off = 1; off < 16; off <<= 1) {
#pragma unroll
            for (int i = 0; i < 4; ++i) mx[i] = fmaxf(mx[i], __shfl_xor(mx[i], off));
        }
        float mnew[4], alpha[4];
#pragma unroll
        for (int i = 0; i < 4; ++i) {
            mnew[i] = fmaxf(mrun[i], mx[i]);
            alpha[i] = __expf(mrun[i] - mnew[i]);
            p0[i] = __expf(s0[i] - mnew[i]);
            p1[i] = __expf(s1[i] - mnew[i]);
            rs[i] = p0[i] + p1[i];
        }
#pragma unroll
        for (int off = 1; off < 16; off <<= 1) {
#pragma unroll
            for (int i = 0; i < 4; ++i) rs[i] += __shfl_xor(rs[i], off);
        }
#pragma unroll
        for (int i = 0; i < 4; ++i) {
            lrun[i] = lrun[i] * alpha[i] + rs[i];
            mrun[i] = mnew[i];
        }

        // transpose P (D-layout -> A-layout) through LDS
        unsigned short* pb = pbuf[wid];
#pragma unroll
        for (int i = 0; i < 4; ++i) {
            const int prow = 4 * g + i;
            pb[prow * 40 + r]      = f32_to_bf16(p0[i]);
            pb[prow * 40 + 16 + r] = f32_to_bf16(p1[i]);
        }
        __syncthreads();
        bf16x8 pf = *reinterpret_cast<const bf16x8*>(&pb[r * 40 + g * 8]);

        // rescale running accumulator, then PV
#pragma unroll
        for (int dt = 0; dt < 4; ++dt) {
#pragma unroll
            for (int i = 0; i < 4; ++i) acc[dt][i] *= alpha[i];
        }
#pragma unroll
        for (int dt = 0; dt < 4; ++dt) {
            bf16x8 vf;
#pragma unroll
            for (int i2 = 0; i2 < 8; ++i2) {
                const int vrow = 8 * g + i2;
                const int vcol = dt * 16 + r;
                vf[i2] = (short)sV[vrow * 64 + (vcol ^ ((vrow & 7) * 8))];
            }
            acc[dt] = MFMA_BF16(pf, vf, acc[dt]);
        }
    }

    // epilogue: ctx[b, s, h*64+d] bf16 (A-matrix layout for out-proj GEMM)
    const int b = hb >> 4, hh = hb & 15;
#pragma unroll
    for (int dt = 0; dt < 4; ++dt) {
#pragma unroll
        for (int i = 0; i < 4; ++i) {
            const int qrow = q0 + 4 * g + i;
            const int d = dt * 16 + r;
            const float val = acc[dt][i] / lrun[i];
            ctx[((size_t)(b * 2048 + qrow)) * 1024 + hh * 64 + d] = f32_to_bf16(val);
        }
    }
}

// ---------------------------------------------------------------- launch
extern "C" void kernel_launch(void* const* d_in, const int* in_sizes, int n_in,
                              void* d_out, int out_size, void* d_ws, size_t ws_size,
                              hipStream_t stream) {
    const float* x     = (const float*)d_in[0];   // [2,2048,1024]
    const float* w_qkv = (const float*)d_in[1];   // [3072,1024]
    const float* w_out = (const float*)d_in[2];   // [1024,1024]
    float* out = (float*)d_out;                   // [2,2048,1024]

    // workspace layout (bf16 = ushort), total ~48 MB
    unsigned short* xb    = (unsigned short*)d_ws;        // 4194304
    unsigned short* wqkvb = xb + 4194304;                  // 3145728
    unsigned short* woutb = wqkvb + 3145728;               // 1048576
    unsigned short* qB    = woutb + 1048576;               // 4194304  [b,h,s,64]
    unsigned short* kB    = qB + 4194304;                  // 4194304
    unsigned short* vB    = kB + 4194304;                  // 4194304
    unsigned short* ctxB  = vB + 4194304;                  // 4194304  [b,s,1024]

    cast_f32_bf16<<<4096, 256, 0, stream>>>(x, xb, 1048576);
    cast_f32_bf16<<<3072, 256, 0, stream>>>(w_qkv, wqkvb, 786432);
    cast_f32_bf16<<<1024, 256, 0, stream>>>(w_out, woutb, 262144);

    // QKV: [4096,1024] x [3072,1024]^T
    gemm_bt<0><<<dim3(24, 32), 256, 0, stream>>>(xb, wqkvb, 3072, 1024, qB, kB, vB, nullptr);

    // attention: 32 heads x 32 q-blocks
    attn_kernel<<<1024, 256, 0, stream>>>(qB, kB, vB, ctxB);

    // out-proj: [4096,1024] x [1024,1024]^T -> fp32 out
    gemm_bt<1><<<dim3(8, 32), 256, 0, stream>>>(ctxB, woutb, 1024, 1024, nullptr, nullptr, nullptr, out);
}

// Round 2
// 164.359 us; speedup vs baseline: 1.6707x; 1.6707x over previous
//
#include <hip/hip_runtime.h>

typedef __attribute__((ext_vector_type(8))) short bf16x8;
typedef __attribute__((ext_vector_type(4))) float f32x4;
typedef __attribute__((ext_vector_type(4))) unsigned int u32x4;

#define MFMA_BF16(A, B, C) __builtin_amdgcn_mfma_f32_16x16x32_bf16((A), (B), (C), 0, 0, 0)

static __device__ __forceinline__ unsigned short f32_to_bf16(float f) {
    unsigned int u = __builtin_bit_cast(unsigned int, f);
    u += 0x7fffu + ((u >> 16) & 1u);
    return (unsigned short)(u >> 16);
}

static __device__ __forceinline__ unsigned int pack2_bf16(float lo, float hi) {
    return (unsigned int)f32_to_bf16(lo) | ((unsigned int)f32_to_bf16(hi) << 16);
}

// async global->LDS, 16B per lane; LDS dest = wave-uniform base + lane*16
static __device__ __forceinline__ void gload16(const unsigned short* g, unsigned short* l) {
    __builtin_amdgcn_global_load_lds(
        (const __attribute__((address_space(1))) unsigned int*)g,
        (__attribute__((address_space(3))) unsigned int*)l, 16, 0, 0);
}

// ---------------------------------------------------------------- cast f32 -> bf16
__global__ void cast_f32_bf16(const float* __restrict__ in, unsigned short* __restrict__ out, int n4) {
    int i = blockIdx.x * 256 + threadIdx.x;
    if (i >= n4) return;
    float4 v = reinterpret_cast<const float4*>(in)[i];
    ushort4 o;
    o.x = f32_to_bf16(v.x);
    o.y = f32_to_bf16(v.y);
    o.z = f32_to_bf16(v.z);
    o.w = f32_to_bf16(v.w);
    reinterpret_cast<ushort4*>(out)[i] = o;
}

// ---------------------------------------------------------------- GEMM  C = A[M,K] * B[N,K]^T
// MODE 0: QKV epilogue (q/k -> [b,h,s,64] bf16, q scaled 0.125; V TRANSPOSED -> [b,h,d,s])
// MODE 1: out projection epilogue (fp32 to d_out [M,N])
template <int MODE>
__global__ __launch_bounds__(256, 2)
void gemm_bt(const unsigned short* __restrict__ Ag,
             const unsigned short* __restrict__ Bg,
             int N, int K,
             unsigned short* __restrict__ qO,
             unsigned short* __restrict__ kO,
             unsigned short* __restrict__ vO,
             float* __restrict__ fO)
{
    constexpr int BM = 128, BN = 128, BK = 64;
    __shared__ unsigned short sA[BM * BK];
    __shared__ unsigned short sB[BN * BK];

    const int m0 = blockIdx.y * BM;
    const int n0 = blockIdx.x * BN;
    const int t = threadIdx.x;
    const int lane = t & 63;
    const int wid = t >> 6;
    const int wr = wid >> 1, wc = wid & 1;   // 2x2 wave grid, 64x64 per wave
    const int g = lane >> 4, r = lane & 15;
    const int lr8 = lane >> 3, lc = lane & 7;

    const f32x4 fzero = {0.f, 0.f, 0.f, 0.f};
    f32x4 acc[4][4];
#pragma unroll
    for (int mi = 0; mi < 4; ++mi)
#pragma unroll
        for (int ni = 0; ni < 4; ++ni) acc[mi][ni] = fzero;

    for (int k0 = 0; k0 < K; k0 += BK) {
        __syncthreads();
        // global_load_lds staging: linear LDS dest, XOR-pre-swizzled global source.
#pragma unroll
        for (int rep = 0; rep < 4; ++rep) {
            const int rbase = rep * 32 + wid * 8;       // wave-uniform
            const int row = rbase + lr8;
            const int cs = lc ^ (row & 7);              // 16B-chunk swizzle
            gload16(&Ag[(size_t)(m0 + row) * K + k0 + cs * 8], &sA[rbase * 64]);
            gload16(&Bg[(size_t)(n0 + row) * K + k0 + cs * 8], &sB[rbase * 64]);
        }
        __syncthreads();

#pragma unroll
        for (int ks = 0; ks < BK; ks += 32) {
            const int c = (ks >> 3) + g;
            bf16x8 af[4], bfr[4];
#pragma unroll
            for (int mi = 0; mi < 4; ++mi) {
                const int row = wr * 64 + mi * 16 + r;
                af[mi] = *reinterpret_cast<const bf16x8*>(&sA[row * BK + ((c * 8) ^ ((row & 7) * 8))]);
            }
#pragma unroll
            for (int ni = 0; ni < 4; ++ni) {
                const int row = wc * 64 + ni * 16 + r;
                bfr[ni] = *reinterpret_cast<const bf16x8*>(&sB[row * BK + ((c * 8) ^ ((row & 7) * 8))]);
            }
#pragma unroll
            for (int mi = 0; mi < 4; ++mi)
#pragma unroll
                for (int ni = 0; ni < 4; ++ni)
                    acc[mi][ni] = MFMA_BF16(af[mi], bfr[ni], acc[mi][ni]);
        }
    }

    // Epilogue. D layout: row = 4*g + i, col = r (within each 16x16 fragment).
#pragma unroll
    for (int mi = 0; mi < 4; ++mi) {
#pragma unroll
        for (int ni = 0; ni < 4; ++ni) {
            const int mbase = m0 + wr * 64 + mi * 16 + 4 * g;   // multiple of 4
            const int n = n0 + wc * 64 + ni * 16 + r;
            if (MODE == 0) {
                const int b = mbase >> 11, s = mbase & 2047;    // uniform over i (aligned 4)
                const int which = n >> 10;       // 0=q 1=k 2=v  (uniform per fragment)
                const int h = (n >> 6) & 15;
                const int d = n & 63;
                if (which == 2) {
                    // V transposed: [b,h,d,s]; 4 consecutive s -> packed 8B store
                    ushort4 v4;
                    v4.x = f32_to_bf16(acc[mi][ni][0]);
                    v4.y = f32_to_bf16(acc[mi][ni][1]);
                    v4.z = f32_to_bf16(acc[mi][ni][2]);
                    v4.w = f32_to_bf16(acc[mi][ni][3]);
                    *reinterpret_cast<ushort4*>(&vO[(((size_t)(b * 16 + h)) * 64 + d) * 2048 + s]) = v4;
                } else {
                    const size_t dst = (((size_t)(b * 16 + h)) * 2048 + s) * 64 + d;
#pragma unroll
                    for (int i = 0; i < 4; ++i) {
                        const float val = acc[mi][ni][i];
                        if (which == 0) qO[dst + (size_t)i * 64] = f32_to_bf16(val * 0.125f);
                        else            kO[dst + (size_t)i * 64] = f32_to_bf16(val);
                    }
                }
            } else {
#pragma unroll
                for (int i = 0; i < 4; ++i)
                    fO[(size_t)(mbase + i) * N + n] = acc[mi][ni][i];
            }
        }
    }
}

// ---------------------------------------------------------------- flash attention v2
// grid 512 = 32 heads * 16 qblocks (XCD-swizzled). 4 waves * 32 q-rows = 128 q/block.
// KVBLK=64. Swapped QK^T (A=K, B=Q) -> in-register softmax. V pre-transposed [b,h,d,s].
__global__ __launch_bounds__(256, 1)
void attn_kernel(const unsigned short* __restrict__ Q,
                 const unsigned short* __restrict__ Kg,
                 const unsigned short* __restrict__ Vtg,
                 unsigned short* __restrict__ ctx)
{
    const int S = 2048;
    const int bid = blockIdx.x;
    const int swz = (bid & 7) * 64 + (bid >> 3);   // bijective XCD swizzle (512 % 8 == 0)
    const int hb = swz >> 4;                       // 0..31 = b*16+h
    const int qb = swz & 15;                       // 0..15
    const unsigned short* Qh = Q + (size_t)hb * S * 64;
    const unsigned short* Kh = Kg + (size_t)hb * S * 64;
    const unsigned short* Vh = Vtg + (size_t)hb * 64 * S;   // [d][s]

    const int t = threadIdx.x, lane = t & 63, wid = t >> 6;
    const int g = lane >> 4, r = lane & 15;
    const int lr8 = lane >> 3, lc = lane & 7;
    const int q0 = qb * 128 + wid * 32;

    __shared__ unsigned short sK[64 * 64];    // [k][d] chunks XOR-swizzled
    __shared__ unsigned short sVt[64 * 64];   // [d][k] chunks XOR-swizzled

    // Q fragments in registers for whole kernel (B-operand: col q = r, elems d = g*8+j)
    bf16x8 qf[2][2];
#pragma unroll
    for (int qt = 0; qt < 2; ++qt)
#pragma unroll
        for (int h = 0; h < 2; ++h)
            qf[qt][h] = *reinterpret_cast<const bf16x8*>(
                &Qh[(size_t)(q0 + qt * 16 + r) * 64 + h * 32 + g * 8]);

    const f32x4 fzero = {0.f, 0.f, 0.f, 0.f};
    f32x4 acc[2][4];
#pragma unroll
    for (int qt = 0; qt < 2; ++qt)
#pragma unroll
        for (int dt = 0; dt < 4; ++dt) acc[qt][dt] = fzero;
    float mrun[2] = {-1e30f, -1e30f}, lrun[2] = {0.f, 0.f};

    const int src0 = ((g & 1) * 2) * 16 + r;   // P-redistribution source lanes
    const int src1 = src0 + 16;
    const bool hi = (g >= 2);

    for (int k0 = 0; k0 < S; k0 += 64) {
        __syncthreads();
#pragma unroll
        for (int rep = 0; rep < 2; ++rep) {
            const int rbase = wid * 16 + rep * 8;   // wave-uniform
            const int row = rbase + lr8;
            const int cs = lc ^ (row & 7);
            gload16(&Kh[(size_t)(k0 + row) * 64 + cs * 8], &sK[rbase * 64]);
            gload16(&Vh[(size_t)row * S + k0 + cs * 8], &sVt[rbase * 64]);
        }
        __syncthreads();

        // S^T = K * Q^T : D[k][q], lane holds col q=r, rows k = kc*16 + 4g+i
        f32x4 st[2][4];
#pragma unroll
        for (int qt = 0; qt < 2; ++qt)
#pragma unroll
            for (int kc = 0; kc < 4; ++kc) st[qt][kc] = fzero;
#pragma unroll
        for (int kc = 0; kc < 4; ++kc) {
            const int rowk = kc * 16 + r;
            const int sw = rowk & 7;
#pragma unroll
            for (int h = 0; h < 2; ++h) {
                bf16x8 kf = *reinterpret_cast<const bf16x8*>(
                    &sK[rowk * 64 + (((h * 4 + g) ^ sw) * 8)]);
                st[0][kc] = MFMA_BF16(kf, qf[0][h], st[0][kc]);
                st[1][kc] = MFMA_BF16(kf, qf[1][h], st[1][kc]);
            }
        }

        // online softmax (per lane: q-row r; 16 k-values local, 2 shfl rounds across g)
        float alpha[2];
        unsigned int ppk[2][8];
#pragma unroll
        for (int qt = 0; qt < 2; ++qt) {
            float mx = st[qt][0][0];
#pragma unroll
            for (int kc = 0; kc < 4; ++kc)
#pragma unroll
                for (int i = 0; i < 4; ++i) mx = fmaxf(mx, st[qt][kc][i]);
            mx = fmaxf(mx, __shfl_xor(mx, 16));
            mx = fmaxf(mx, __shfl_xor(mx, 32));
            const float mnew = fmaxf(mrun[qt], mx);
            alpha[qt] = __expf(mrun[qt] - mnew);
            mrun[qt] = mnew;
            float sum = 0.f;
#pragma unroll
            for (int kc = 0; kc < 4; ++kc)
#pragma unroll
                for (int i = 0; i < 4; ++i) {
                    const float p = __expf(st[qt][kc][i] - mnew);
                    st[qt][kc][i] = p;
                    sum += p;
                }
            sum += __shfl_xor(sum, 16);
            sum += __shfl_xor(sum, 32);
            lrun[qt] = lrun[qt] * alpha[qt] + sum;
#pragma unroll
            for (int kc = 0; kc < 4; ++kc) {
                ppk[qt][kc * 2 + 0] = pack2_bf16(st[qt][kc][0], st[qt][kc][1]);
                ppk[qt][kc * 2 + 1] = pack2_bf16(st[qt][kc][2], st[qt][kc][3]);
            }
        }

        // rescale accumulator rows (acc row i is q-row 4g+i; its alpha lives in lane 4g+i)
#pragma unroll
        for (int qt = 0; qt < 2; ++qt) {
            float ar[4];
#pragma unroll
            for (int i = 0; i < 4; ++i) ar[i] = __shfl(alpha[qt], 4 * g + i);
#pragma unroll
            for (int dt = 0; dt < 4; ++dt)
#pragma unroll
                for (int i = 0; i < 4; ++i) acc[qt][dt][i] *= ar[i];
        }

        // redistribute P into A-fragments: pf[c] word w = P[r][c*32+g*8+2w..+1]
        bf16x8 pf[2][2];
#pragma unroll
        for (int qt = 0; qt < 2; ++qt) {
#pragma unroll
            for (int c = 0; c < 2; ++c) {
                u32x4 wv;
#pragma unroll
                for (int w = 0; w < 4; ++w) {
                    const int srcl = (w < 2) ? src0 : src1;
                    const unsigned int a = (unsigned int)__shfl((int)ppk[qt][(2 * c) * 2 + (w & 1)], srcl);
                    const unsigned int b = (unsigned int)__shfl((int)ppk[qt][(2 * c + 1) * 2 + (w & 1)], srcl);
                    wv[w] = hi ? b : a;
                }
                pf[qt][c] = __builtin_bit_cast(bf16x8, wv);
            }
        }

        // PV: A = P fragments, B = V^T from LDS (col d = r, elems k = g*8+j)
#pragma unroll
        for (int dt = 0; dt < 4; ++dt) {
            const int rowd = dt * 16 + r;
            const int sw = rowd & 7;
#pragma unroll
            for (int c = 0; c < 2; ++c) {
                bf16x8 vf = *reinterpret_cast<const bf16x8*>(
                    &sVt[rowd * 64 + (((c * 4 + g) ^ sw) * 8)]);
                acc[0][dt] = MFMA_BF16(pf[0][c], vf, acc[0][dt]);
                acc[1][dt] = MFMA_BF16(pf[1][c], vf, acc[1][dt]);
            }
        }
    }

    // epilogue: ctx[b, s, h*64+d] bf16
    const int b = hb >> 4, hh = hb & 15;
#pragma unroll
    for (int qt = 0; qt < 2; ++qt) {
        float li[4];
#pragma unroll
        for (int i = 0; i < 4; ++i) li[i] = __shfl(lrun[qt], 4 * g + i);
#pragma unroll
        for (int dt = 0; dt < 4; ++dt) {
#pragma unroll
            for (int i = 0; i < 4; ++i) {
                const int qrow = q0 + qt * 16 + 4 * g + i;
                ctx[((size_t)(b * 2048 + qrow)) * 1024 + hh * 64 + dt * 16 + r] =
                    f32_to_bf16(acc[qt][dt][i] / li[i]);
            }
        }
    }
}

// ---------------------------------------------------------------- launch
extern "C" void kernel_launch(void* const* d_in, const int* in_sizes, int n_in,
                              void* d_out, int out_size, void* d_ws, size_t ws_size,
                              hipStream_t stream) {
    const float* x     = (const float*)d_in[0];   // [2,2048,1024]
    const float* w_qkv = (const float*)d_in[1];   // [3072,1024]
    const float* w_out = (const float*)d_in[2];   // [1024,1024]
    float* out = (float*)d_out;                   // [2,2048,1024]

    unsigned short* xb    = (unsigned short*)d_ws;         // 4194304
    unsigned short* wqkvb = xb + 4194304;                  // 3145728
    unsigned short* woutb = wqkvb + 3145728;               // 1048576
    unsigned short* qB    = woutb + 1048576;               // 4194304  [b,h,s,64]
    unsigned short* kB    = qB + 4194304;                  // 4194304  [b,h,s,64]
    unsigned short* vB    = kB + 4194304;                  // 4194304  [b,h,d,s] (transposed)
    unsigned short* ctxB  = vB + 4194304;                  // 4194304  [b,s,1024]

    cast_f32_bf16<<<4096, 256, 0, stream>>>(x, xb, 1048576);
    cast_f32_bf16<<<3072, 256, 0, stream>>>(w_qkv, wqkvb, 786432);
    cast_f32_bf16<<<1024, 256, 0, stream>>>(w_out, woutb, 262144);

    // QKV: [4096,1024] x [3072,1024]^T
    gemm_bt<0><<<dim3(24, 32), 256, 0, stream>>>(xb, wqkvb, 3072, 1024, qB, kB, vB, nullptr);

    // attention: 32 heads x 16 q-blocks (128 q-rows each)
    attn_kernel<<<512, 256, 0, stream>>>(qB, kB, vB, ctxB);

    // out-proj: [4096,1024] x [1024,1024]^T -> fp32 out
    gemm_bt<1><<<dim3(8, 32), 256, 0, stream>>>(ctxB, woutb, 1024, 1024, nullptr, nullptr, nullptr, out);
}

// Round 5
// 128.393 us; speedup vs baseline: 2.1387x; 1.2801x over previous
//
#include <hip/hip_runtime.h>

typedef __attribute__((ext_vector_type(8))) short bf16x8;
typedef __attribute__((ext_vector_type(4))) float f32x4;
typedef __attribute__((ext_vector_type(16))) float f32x16;
typedef __attribute__((ext_vector_type(4))) unsigned int u32x4;

#define MFMA16(A, B, C) __builtin_amdgcn_mfma_f32_16x16x32_bf16((A), (B), (C), 0, 0, 0)
#define MFMA32(A, B, C) __builtin_amdgcn_mfma_f32_32x32x16_bf16((A), (B), (C), 0, 0, 0)

static __device__ __forceinline__ unsigned short f32_to_bf16(float f) {
    unsigned int u = __builtin_bit_cast(unsigned int, f);
    u += 0x7fffu + ((u >> 16) & 1u);
    return (unsigned short)(u >> 16);
}

// pack two f32 -> one u32 of two bf16 (RNE); lo -> bits 0..15, hi -> bits 16..31
static __device__ __forceinline__ unsigned int pk2(float lo, float hi) {
    return (unsigned int)f32_to_bf16(lo) | ((unsigned int)f32_to_bf16(hi) << 16);
}

// async global->LDS, 16B per lane; LDS dest = wave-uniform base + lane*16
static __device__ __forceinline__ void gload16(const unsigned short* g, unsigned short* l) {
    __builtin_amdgcn_global_load_lds(
        (const __attribute__((address_space(1))) unsigned int*)g,
        (__attribute__((address_space(3))) unsigned int*)l, 16, 0, 0);
}

// fold softmax scale and log2(e) into q so attention uses exp2 directly
#define QSCALE 0.18033688011112042f   // 0.125 * log2(e)

// ---------------------------------------------------------------- fused cast f32 -> bf16 (x, w_qkv, w_out)
__global__ void cast3_f32_bf16(const float* __restrict__ x, const float* __restrict__ wq,
                               const float* __restrict__ wo,
                               unsigned short* __restrict__ xb, unsigned short* __restrict__ wqb,
                               unsigned short* __restrict__ wob) {
    int i = blockIdx.x * 256 + threadIdx.x;   // 2097152 float4 groups total
    const float* src;
    unsigned short* dst;
    int off;
    if (i < 1048576)      { src = x;  dst = xb;  off = i; }
    else if (i < 1835008) { src = wq; dst = wqb; off = i - 1048576; }
    else                  { src = wo; dst = wob; off = i - 1835008; }
    float4 v = reinterpret_cast<const float4*>(src)[off];
    ushort4 o;
    o.x = f32_to_bf16(v.x);
    o.y = f32_to_bf16(v.y);
    o.z = f32_to_bf16(v.z);
    o.w = f32_to_bf16(v.w);
    reinterpret_cast<ushort4*>(dst)[off] = o;
}

// ---------------------------------------------------------------- GEMM  C = A[M,K] * B[N,K]^T
// MODE 0: QKV epilogue (q/k -> [b,h,s,64] bf16, q scaled by QSCALE; V TRANSPOSED -> [b,h,d,s])
// MODE 1: out projection epilogue (fp32 to d_out [M,N])
template <int MODE>
__global__ __launch_bounds__(256, 2)
void gemm_bt(const unsigned short* __restrict__ Ag,
             const unsigned short* __restrict__ Bg,
             int N, int K,
             unsigned short* __restrict__ qO,
             unsigned short* __restrict__ kO,
             unsigned short* __restrict__ vO,
             float* __restrict__ fO)
{
    constexpr int BM = 128, BN = 128, BK = 64;
    __shared__ unsigned short sA[BM * BK];
    __shared__ unsigned short sB[BN * BK];

    const int m0 = blockIdx.y * BM;
    const int n0 = blockIdx.x * BN;
    const int t = threadIdx.x;
    const int lane = t & 63;
    const int wid = t >> 6;
    const int wr = wid >> 1, wc = wid & 1;   // 2x2 wave grid, 64x64 per wave
    const int g = lane >> 4, r = lane & 15;
    const int lr8 = lane >> 3, lc = lane & 7;

    const f32x4 fzero = {0.f, 0.f, 0.f, 0.f};
    f32x4 acc[4][4];
#pragma unroll
    for (int mi = 0; mi < 4; ++mi)
#pragma unroll
        for (int ni = 0; ni < 4; ++ni) acc[mi][ni] = fzero;

    for (int k0 = 0; k0 < K; k0 += BK) {
        __syncthreads();
        // global_load_lds staging: linear LDS dest, XOR-pre-swizzled global source.
#pragma unroll
        for (int rep = 0; rep < 4; ++rep) {
            const int rbase = rep * 32 + wid * 8;       // wave-uniform
            const int row = rbase + lr8;
            const int cs = lc ^ (row & 7);              // 16B-chunk swizzle
            gload16(&Ag[(size_t)(m0 + row) * K + k0 + cs * 8], &sA[rbase * 64]);
            gload16(&Bg[(size_t)(n0 + row) * K + k0 + cs * 8], &sB[rbase * 64]);
        }
        __syncthreads();

#pragma unroll
        for (int ks = 0; ks < BK; ks += 32) {
            const int c = (ks >> 3) + g;
            bf16x8 af[4], bfr[4];
#pragma unroll
            for (int mi = 0; mi < 4; ++mi) {
                const int row = wr * 64 + mi * 16 + r;
                af[mi] = *reinterpret_cast<const bf16x8*>(&sA[row * BK + ((c * 8) ^ ((row & 7) * 8))]);
            }
#pragma unroll
            for (int ni = 0; ni < 4; ++ni) {
                const int row = wc * 64 + ni * 16 + r;
                bfr[ni] = *reinterpret_cast<const bf16x8*>(&sB[row * BK + ((c * 8) ^ ((row & 7) * 8))]);
            }
#pragma unroll
            for (int mi = 0; mi < 4; ++mi)
#pragma unroll
                for (int ni = 0; ni < 4; ++ni)
                    acc[mi][ni] = MFMA16(af[mi], bfr[ni], acc[mi][ni]);
        }
    }

    // Epilogue. D layout (16x16): row = 4*g + i, col = r.
#pragma unroll
    for (int mi = 0; mi < 4; ++mi) {
#pragma unroll
        for (int ni = 0; ni < 4; ++ni) {
            const int mbase = m0 + wr * 64 + mi * 16 + 4 * g;   // multiple of 4
            const int n = n0 + wc * 64 + ni * 16 + r;
            if (MODE == 0) {
                const int b = mbase >> 11, s = mbase & 2047;    // uniform over i (aligned 4)
                const int which = n >> 10;       // 0=q 1=k 2=v  (uniform per fragment)
                const int h = (n >> 6) & 15;
                const int d = n & 63;
                if (which == 2) {
                    // V transposed: [b,h,d,s]; 4 consecutive s -> packed 8B store
                    ushort4 v4;
                    v4.x = f32_to_bf16(acc[mi][ni][0]);
                    v4.y = f32_to_bf16(acc[mi][ni][1]);
                    v4.z = f32_to_bf16(acc[mi][ni][2]);
                    v4.w = f32_to_bf16(acc[mi][ni][3]);
                    *reinterpret_cast<ushort4*>(&vO[(((size_t)(b * 16 + h)) * 64 + d) * 2048 + s]) = v4;
                } else {
                    const size_t dst = (((size_t)(b * 16 + h)) * 2048 + s) * 64 + d;
#pragma unroll
                    for (int i = 0; i < 4; ++i) {
                        const float val = acc[mi][ni][i];
                        if (which == 0) qO[dst + (size_t)i * 64] = f32_to_bf16(val * QSCALE);
                        else            kO[dst + (size_t)i * 64] = f32_to_bf16(val);
                    }
                }
            } else {
#pragma unroll
                for (int i = 0; i < 4; ++i)
                    fO[(size_t)(mbase + i) * N + n] = acc[mi][ni][i];
            }
        }
    }
}

// ---------------------------------------------------------------- flash attention v3b (32x32 MFMA geometry)
// grid 512 = 32 heads * 16 qblocks (XCD-swizzled). 4 waves * 32 q-rows = 128 q/block. KVBLK=64.
// Swapped QK^T: st[k][q], lane owns q = lane&31 -> softmax lane-local.
// K A-operand rows fed through involution pi(r) = bitswap(r, bits 2<->3), so that the
// C/D row set owned by each lane-half lands CONTIGUOUS in k: lane's st regs 0..15 hold
// k = {8*lhi+0..7, 16+8*lhi+0..7} in order == exactly the PV B-fragment slots. Softmax is
// permutation-invariant, so pi needs no compensation anywhere else. Zero cross-lane P ops.
// Swapped PV: acc = O^T[d][q] -> alpha rescale is lane-uniform scalar.
__global__ __launch_bounds__(256, 2)
void attn_kernel(const unsigned short* __restrict__ Q,
                 const unsigned short* __restrict__ Kg,
                 const unsigned short* __restrict__ Vtg,
                 unsigned short* __restrict__ ctx)
{
    const int S = 2048;
    const int bid = blockIdx.x;
    const int swz = (bid & 7) * 64 + (bid >> 3);   // bijective XCD swizzle (512 % 8 == 0)
    const int hb = swz >> 4;                       // 0..31 = b*16+h
    const int qb = swz & 15;                       // 0..15
    const unsigned short* Qh = Q + (size_t)hb * S * 64;
    const unsigned short* Kh = Kg + (size_t)hb * S * 64;
    const unsigned short* Vh = Vtg + (size_t)hb * 64 * S;   // [d][s]

    const int t = threadIdx.x, lane = t & 63, wid = t >> 6;
    const int l31 = lane & 31, lhi = lane >> 5;
    const int lr8 = lane >> 3, lc = lane & 7;
    const int q0 = qb * 128 + wid * 32;

    // pi(l31): swap bits 2 and 3 (involution)
    const int krow = (l31 & 19) | ((l31 & 4) << 1) | ((l31 & 8) >> 1);
    const int ksw = krow & 7;

    __shared__ unsigned short sK[2][64 * 64];    // [k][d], 16B-chunk XOR-swizzled
    __shared__ unsigned short sVt[2][64 * 64];   // [d][k], 16B-chunk XOR-swizzled

    // Q B-fragments (col q = l31, contraction d = dstep*16 + lhi*8 + j), in regs all kernel
    bf16x8 qf[4];
#pragma unroll
    for (int dstep = 0; dstep < 4; ++dstep)
        qf[dstep] = *reinterpret_cast<const bf16x8*>(
            &Qh[(size_t)(q0 + l31) * 64 + dstep * 16 + lhi * 8]);

    f32x16 acc[2];   // O^T: acc[dt], row d = 32dt + (reg&3)+8*(reg>>2)+4*lhi, col q = l31
#pragma unroll
    for (int dt = 0; dt < 2; ++dt)
#pragma unroll
        for (int i = 0; i < 16; ++i) acc[dt][i] = 0.f;
    float mrun = -1e30f, lrun = 0.f;

#define STAGE(buf, k0)                                                                   \
    {                                                                                    \
        _Pragma("unroll")                                                                \
        for (int rep = 0; rep < 2; ++rep) {                                              \
            const int rbase = wid * 16 + rep * 8;                                        \
            const int row = rbase + lr8;                                                 \
            const int cs = lc ^ (row & 7);                                               \
            gload16(&Kh[(size_t)((k0) + row) * 64 + cs * 8], &sK[buf][rbase * 64]);      \
            gload16(&Vh[(size_t)row * S + (k0) + cs * 8], &sVt[buf][rbase * 64]);        \
        }                                                                                \
    }

    STAGE(0, 0);
    int cur = 0;

    for (int it = 0; it < 32; ++it) {
        __syncthreads();   // drains vmcnt: tile `it` resident; prev compute done
        if (it < 31) {
            const int kn = (it + 1) * 64;
            if (cur) STAGE(0, kn) else STAGE(1, kn);
        }

        // ---- QK^T (swapped, pi-permuted A rows): st holds S^T[pi-rows][q=l31]
        f32x16 st0, st1;
#pragma unroll
        for (int i = 0; i < 16; ++i) { st0[i] = 0.f; st1[i] = 0.f; }
        __builtin_amdgcn_s_setprio(1);
#pragma unroll
        for (int dstep = 0; dstep < 4; ++dstep) {
            const int c = dstep * 2 + lhi;
            bf16x8 kf0 = *reinterpret_cast<const bf16x8*>(
                &sK[cur][krow * 64 + ((c ^ ksw) * 8)]);
            bf16x8 kf1 = *reinterpret_cast<const bf16x8*>(
                &sK[cur][(32 + krow) * 64 + ((c ^ ksw) * 8)]);
            st0 = MFMA32(kf0, qf[dstep], st0);
            st1 = MFMA32(kf1, qf[dstep], st1);
        }
        __builtin_amdgcn_s_setprio(0);
        // per-lane k values: st0[i] = S[k], k = (i<8 ? 8*lhi+i : 16+8*lhi+(i-8)); st1: +32.

        // ---- online softmax (lane-local: q = l31; column split across lane, lane^32)
        float m8[8];
#pragma unroll
        for (int j = 0; j < 8; ++j)
            m8[j] = fmaxf(fmaxf(st0[j], st0[j + 8]), fmaxf(st1[j], st1[j + 8]));
        float m4a = fmaxf(m8[0], m8[1]), m4b = fmaxf(m8[2], m8[3]);
        float m4c = fmaxf(m8[4], m8[5]), m4d = fmaxf(m8[6], m8[7]);
        float mx = fmaxf(fmaxf(m4a, m4b), fmaxf(m4c, m4d));
        mx = fmaxf(mx, __shfl_xor(mx, 32));

        if (__any(mx > mrun)) {              // exact skip: if mx<=mrun everywhere, alpha==1
            const float mnew = fmaxf(mrun, mx);
            const float alpha = __builtin_amdgcn_exp2f(mrun - mnew);
            mrun = mnew;
            lrun *= alpha;
#pragma unroll
            for (int dt = 0; dt < 2; ++dt)
#pragma unroll
                for (int i = 0; i < 16; ++i) acc[dt][i] *= alpha;
        }

#pragma unroll
        for (int i = 0; i < 16; ++i) {
            st0[i] = __builtin_amdgcn_exp2f(st0[i] - mrun);
            st1[i] = __builtin_amdgcn_exp2f(st1[i] - mrun);
        }
        float s8[8];
#pragma unroll
        for (int j = 0; j < 8; ++j)
            s8[j] = (st0[j] + st0[j + 8]) + (st1[j] + st1[j + 8]);
        float sum = ((s8[0] + s8[1]) + (s8[2] + s8[3])) + ((s8[4] + s8[5]) + (s8[6] + s8[7]));
        sum += __shfl_xor(sum, 32);
        lrun += sum;

        // ---- P^T B-fragments: in-register, in-order (thanks to pi) — no cross-lane ops
        bf16x8 pf[4];
#define PACK8(stv, base, out)                                                  \
        {                                                                      \
            u32x4 wv;                                                          \
            wv[0] = pk2(stv[(base) + 0], stv[(base) + 1]);                     \
            wv[1] = pk2(stv[(base) + 2], stv[(base) + 3]);                     \
            wv[2] = pk2(stv[(base) + 4], stv[(base) + 5]);                     \
            wv[3] = pk2(stv[(base) + 6], stv[(base) + 7]);                     \
            out = __builtin_bit_cast(bf16x8, wv);                              \
        }
        PACK8(st0, 0, pf[0])
        PACK8(st0, 8, pf[1])
        PACK8(st1, 0, pf[2])
        PACK8(st1, 8, pf[3])
#undef PACK8

        // ---- PV (swapped): acc[dt] += V^T_tile * P^T, A row d = l31+32dt, contraction k
        __builtin_amdgcn_s_setprio(1);
#pragma unroll
        for (int dt = 0; dt < 2; ++dt) {
            const int rowd = dt * 32 + l31;
            const int sw = rowd & 7;
#pragma unroll
            for (int ks = 0; ks < 4; ++ks) {
                const int c = ks * 2 + lhi;
                bf16x8 vf = *reinterpret_cast<const bf16x8*>(
                    &sVt[cur][rowd * 64 + ((c ^ sw) * 8)]);
                acc[dt] = MFMA32(vf, pf[ks], acc[dt]);
            }
        }
        __builtin_amdgcn_s_setprio(0);
        cur ^= 1;
    }

    // ---- epilogue: O[q][d] = acc^T / l;  ctx[b, s=q, h*64+d] bf16
    const float rl = __builtin_amdgcn_rcpf(lrun);
    const int b = hb >> 4, hh = hb & 15;
    const size_t rowbase = ((size_t)(b * 2048 + q0 + l31)) * 1024 + hh * 64;
#pragma unroll
    for (int dt = 0; dt < 2; ++dt) {
#pragma unroll
        for (int rg = 0; rg < 4; ++rg) {
            ushort4 o;
            o.x = f32_to_bf16(acc[dt][4 * rg + 0] * rl);
            o.y = f32_to_bf16(acc[dt][4 * rg + 1] * rl);
            o.z = f32_to_bf16(acc[dt][4 * rg + 2] * rl);
            o.w = f32_to_bf16(acc[dt][4 * rg + 3] * rl);
            const int dbase = dt * 32 + rg * 8 + lhi * 4;
            *reinterpret_cast<ushort4*>(&ctx[rowbase + dbase]) = o;
        }
    }
#undef STAGE
}

// ---------------------------------------------------------------- launch
extern "C" void kernel_launch(void* const* d_in, const int* in_sizes, int n_in,
                              void* d_out, int out_size, void* d_ws, size_t ws_size,
                              hipStream_t stream) {
    const float* x     = (const float*)d_in[0];   // [2,2048,1024]
    const float* w_qkv = (const float*)d_in[1];   // [3072,1024]
    const float* w_out = (const float*)d_in[2];   // [1024,1024]
    float* out = (float*)d_out;                   // [2,2048,1024]

    unsigned short* xb    = (unsigned short*)d_ws;         // 4194304
    unsigned short* wqkvb = xb + 4194304;                  // 3145728
    unsigned short* woutb = wqkvb + 3145728;               // 1048576
    unsigned short* qB    = woutb + 1048576;               // 4194304  [b,h,s,64] (scaled by QSCALE)
    unsigned short* kB    = qB + 4194304;                  // 4194304  [b,h,s,64]
    unsigned short* vB    = kB + 4194304;                  // 4194304  [b,h,d,s] (transposed)
    unsigned short* ctxB  = vB + 4194304;                  // 4194304  [b,s,1024]

    cast3_f32_bf16<<<8192, 256, 0, stream>>>(x, w_qkv, w_out, xb, wqkvb, woutb);

    // QKV: [4096,1024] x [3072,1024]^T
    gemm_bt<0><<<dim3(24, 32), 256, 0, stream>>>(xb, wqkvb, 3072, 1024, qB, kB, vB, nullptr);

    // attention: 32 heads x 16 q-blocks (128 q-rows each)
    attn_kernel<<<512, 256, 0, stream>>>(qB, kB, vB, ctxB);

    // out-proj: [4096,1024] x [1024,1024]^T -> fp32 out
    gemm_bt<1><<<dim3(8, 32), 256, 0, stream>>>(ctxB, woutb, 1024, 1024, nullptr, nullptr, nullptr, out);
}

// Round 6
// 124.749 us; speedup vs baseline: 2.2012x; 1.0292x over previous
//
#include <hip/hip_runtime.h>

typedef __attribute__((ext_vector_type(8))) short bf16x8;
typedef __attribute__((ext_vector_type(4))) float f32x4;
typedef __attribute__((ext_vector_type(16))) float f32x16;
typedef __attribute__((ext_vector_type(4))) unsigned int u32x4;

#define MFMA16(A, B, C) __builtin_amdgcn_mfma_f32_16x16x32_bf16((A), (B), (C), 0, 0, 0)
#define MFMA32(A, B, C) __builtin_amdgcn_mfma_f32_32x32x16_bf16((A), (B), (C), 0, 0, 0)

static __device__ __forceinline__ unsigned short f32_to_bf16(float f) {
    unsigned int u = __builtin_bit_cast(unsigned int, f);
    u += 0x7fffu + ((u >> 16) & 1u);
    return (unsigned short)(u >> 16);
}

// pack two f32 -> one u32 of two bf16 (RNE); lo -> bits 0..15, hi -> bits 16..31
static __device__ __forceinline__ unsigned int pk2(float lo, float hi) {
    return (unsigned int)f32_to_bf16(lo) | ((unsigned int)f32_to_bf16(hi) << 16);
}

// async global->LDS, 16B per lane; LDS dest = wave-uniform base + lane*16
static __device__ __forceinline__ void gload16(const unsigned short* g, unsigned short* l) {
    __builtin_amdgcn_global_load_lds(
        (const __attribute__((address_space(1))) unsigned int*)g,
        (__attribute__((address_space(3))) unsigned int*)l, 16, 0, 0);
}

// fold softmax scale and log2(e) into q so attention uses exp2 directly
#define QSCALE 0.18033688011112042f   // 0.125 * log2(e)

// ---------------------------------------------------------------- fused cast f32 -> bf16 (x, w_qkv, w_out)
__global__ void cast3_f32_bf16(const float* __restrict__ x, const float* __restrict__ wq,
                               const float* __restrict__ wo,
                               unsigned short* __restrict__ xb, unsigned short* __restrict__ wqb,
                               unsigned short* __restrict__ wob) {
    int i = blockIdx.x * 256 + threadIdx.x;   // 2097152 float4 groups total
    const float* src;
    unsigned short* dst;
    int off;
    if (i < 1048576)      { src = x;  dst = xb;  off = i; }
    else if (i < 1835008) { src = wq; dst = wqb; off = i - 1048576; }
    else                  { src = wo; dst = wob; off = i - 1835008; }
    float4 v = reinterpret_cast<const float4*>(src)[off];
    ushort4 o;
    o.x = f32_to_bf16(v.x);
    o.y = f32_to_bf16(v.y);
    o.z = f32_to_bf16(v.z);
    o.w = f32_to_bf16(v.w);
    reinterpret_cast<ushort4*>(dst)[off] = o;
}

// ---------------------------------------------------------------- GEMM  C = A[M,K] * B[N,K]^T
// MODE 0: QKV epilogue (q/k -> [b,h,s,64] bf16, q scaled by QSCALE; V TRANSPOSED -> [b,h,d,s])
// MODE 1: out projection epilogue (fp32 to d_out [M,N])
// Fragment reads span 16 rows/instr -> worst alias is 2-way (free, m136); row&7 key suffices.
template <int MODE>
__global__ __launch_bounds__(256, 2)
void gemm_bt(const unsigned short* __restrict__ Ag,
             const unsigned short* __restrict__ Bg,
             int N, int K,
             unsigned short* __restrict__ qO,
             unsigned short* __restrict__ kO,
             unsigned short* __restrict__ vO,
             float* __restrict__ fO)
{
    constexpr int BM = 128, BN = 128, BK = 64;
    __shared__ unsigned short sA[BM * BK];
    __shared__ unsigned short sB[BN * BK];

    const int m0 = blockIdx.y * BM;
    const int n0 = blockIdx.x * BN;
    const int t = threadIdx.x;
    const int lane = t & 63;
    const int wid = t >> 6;
    const int wr = wid >> 1, wc = wid & 1;   // 2x2 wave grid, 64x64 per wave
    const int g = lane >> 4, r = lane & 15;
    const int lr8 = lane >> 3, lc = lane & 7;

    const f32x4 fzero = {0.f, 0.f, 0.f, 0.f};
    f32x4 acc[4][4];
#pragma unroll
    for (int mi = 0; mi < 4; ++mi)
#pragma unroll
        for (int ni = 0; ni < 4; ++ni) acc[mi][ni] = fzero;

    for (int k0 = 0; k0 < K; k0 += BK) {
        __syncthreads();
        // global_load_lds staging: linear LDS dest, XOR-pre-swizzled global source.
#pragma unroll
        for (int rep = 0; rep < 4; ++rep) {
            const int rbase = rep * 32 + wid * 8;       // wave-uniform
            const int row = rbase + lr8;
            const int cs = lc ^ (row & 7);              // 16B-chunk swizzle
            gload16(&Ag[(size_t)(m0 + row) * K + k0 + cs * 8], &sA[rbase * 64]);
            gload16(&Bg[(size_t)(n0 + row) * K + k0 + cs * 8], &sB[rbase * 64]);
        }
        __syncthreads();

#pragma unroll
        for (int ks = 0; ks < BK; ks += 32) {
            const int c = (ks >> 3) + g;
            bf16x8 af[4], bfr[4];
#pragma unroll
            for (int mi = 0; mi < 4; ++mi) {
                const int row = wr * 64 + mi * 16 + r;
                af[mi] = *reinterpret_cast<const bf16x8*>(&sA[row * BK + ((c * 8) ^ ((row & 7) * 8))]);
            }
#pragma unroll
            for (int ni = 0; ni < 4; ++ni) {
                const int row = wc * 64 + ni * 16 + r;
                bfr[ni] = *reinterpret_cast<const bf16x8*>(&sB[row * BK + ((c * 8) ^ ((row & 7) * 8))]);
            }
#pragma unroll
            for (int mi = 0; mi < 4; ++mi)
#pragma unroll
                for (int ni = 0; ni < 4; ++ni)
                    acc[mi][ni] = MFMA16(af[mi], bfr[ni], acc[mi][ni]);
        }
    }

    // Epilogue. D layout (16x16): row = 4*g + i, col = r.
#pragma unroll
    for (int mi = 0; mi < 4; ++mi) {
#pragma unroll
        for (int ni = 0; ni < 4; ++ni) {
            const int mbase = m0 + wr * 64 + mi * 16 + 4 * g;   // multiple of 4
            const int n = n0 + wc * 64 + ni * 16 + r;
            if (MODE == 0) {
                const int b = mbase >> 11, s = mbase & 2047;    // uniform over i (aligned 4)
                const int which = n >> 10;       // 0=q 1=k 2=v  (uniform per fragment)
                const int h = (n >> 6) & 15;
                const int d = n & 63;
                if (which == 2) {
                    // V transposed: [b,h,d,s]; 4 consecutive s -> packed 8B store
                    ushort4 v4;
                    v4.x = f32_to_bf16(acc[mi][ni][0]);
                    v4.y = f32_to_bf16(acc[mi][ni][1]);
                    v4.z = f32_to_bf16(acc[mi][ni][2]);
                    v4.w = f32_to_bf16(acc[mi][ni][3]);
                    *reinterpret_cast<ushort4*>(&vO[(((size_t)(b * 16 + h)) * 64 + d) * 2048 + s]) = v4;
                } else {
                    const size_t dst = (((size_t)(b * 16 + h)) * 2048 + s) * 64 + d;
#pragma unroll
                    for (int i = 0; i < 4; ++i) {
                        const float val = acc[mi][ni][i];
                        if (which == 0) qO[dst + (size_t)i * 64] = f32_to_bf16(val * QSCALE);
                        else            kO[dst + (size_t)i * 64] = f32_to_bf16(val);
                    }
                }
            } else {
#pragma unroll
                for (int i = 0; i < 4; ++i)
                    fO[(size_t)(mbase + i) * N + n] = acc[mi][ni][i];
            }
        }
    }
}

// ---------------------------------------------------------------- flash attention v3c (32x32 MFMA geometry)
// grid 512 = 32 heads * 16 qblocks (XCD-swizzled). 4 waves * 32 q-rows = 128 q/block. KVBLK=64.
// Swapped QK^T: st[k][q], lane owns q = lane&31 -> softmax lane-local.
// K A-operand rows fed through involution pi(r) = bitswap(r, bits 2<->3) so the lane's 16
// st regs are contiguous in k == PV B-fragment slots (zero cross-lane P ops).
// Swapped PV: acc = O^T[d][q] -> alpha rescale lane-uniform. T13 defer-rescale THR=8.
// LDS swizzle key = (row&7)^((row>>3)&3): fragment reads span 32 rows/instr; the 4 mod-8
// row aliases get distinct keys -> conflict-free (row&7 alone left a 4-way conflict).
__global__ __launch_bounds__(256, 2)
void attn_kernel(const unsigned short* __restrict__ Q,
                 const unsigned short* __restrict__ Kg,
                 const unsigned short* __restrict__ Vtg,
                 unsigned short* __restrict__ ctx)
{
    const int S = 2048;
    const int bid = blockIdx.x;
    const int swz = (bid & 7) * 64 + (bid >> 3);   // bijective XCD swizzle (512 % 8 == 0)
    const int hb = swz >> 4;                       // 0..31 = b*16+h
    const int qb = swz & 15;                       // 0..15
    const unsigned short* Qh = Q + (size_t)hb * S * 64;
    const unsigned short* Kh = Kg + (size_t)hb * S * 64;
    const unsigned short* Vh = Vtg + (size_t)hb * 64 * S;   // [d][s]

    const int t = threadIdx.x, lane = t & 63, wid = t >> 6;
    const int l31 = lane & 31, lhi = lane >> 5;
    const int lr8 = lane >> 3, lc = lane & 7;
    const int q0 = qb * 128 + wid * 32;

    // pi(l31): swap bits 2 and 3 (involution)
    const int krow = (l31 & 19) | ((l31 & 4) << 1) | ((l31 & 8) >> 1);
    const int ksw = (krow & 7) ^ ((krow >> 3) & 3);   // valid for rows krow and krow+32
    const int vsw = (l31 & 7) ^ ((l31 >> 3) & 3);     // valid for rows l31 and l31+32

    __shared__ unsigned short sK[2][64 * 64];    // [k][d], 16B-chunk XOR-swizzled
    __shared__ unsigned short sVt[2][64 * 64];   // [d][k], 16B-chunk XOR-swizzled

    // Q B-fragments (col q = l31, contraction d = dstep*16 + lhi*8 + j), in regs all kernel
    bf16x8 qf[4];
#pragma unroll
    for (int dstep = 0; dstep < 4; ++dstep)
        qf[dstep] = *reinterpret_cast<const bf16x8*>(
            &Qh[(size_t)(q0 + l31) * 64 + dstep * 16 + lhi * 8]);

    f32x16 acc[2];   // O^T: acc[dt], row d = 32dt + (reg&3)+8*(reg>>2)+4*lhi, col q = l31
#pragma unroll
    for (int dt = 0; dt < 2; ++dt)
#pragma unroll
        for (int i = 0; i < 16; ++i) acc[dt][i] = 0.f;
    float mrun = -1e30f, lrun = 0.f;

#define STAGE(buf, k0)                                                                   \
    {                                                                                    \
        _Pragma("unroll")                                                                \
        for (int rep = 0; rep < 2; ++rep) {                                              \
            const int rbase = wid * 16 + rep * 8;                                        \
            const int row = rbase + lr8;                                                 \
            const int cs = lc ^ ((row & 7) ^ ((row >> 3) & 3));                          \
            gload16(&Kh[(size_t)((k0) + row) * 64 + cs * 8], &sK[buf][rbase * 64]);      \
            gload16(&Vh[(size_t)row * S + (k0) + cs * 8], &sVt[buf][rbase * 64]);        \
        }                                                                                \
    }

    STAGE(0, 0);
    int cur = 0;

    for (int it = 0; it < 32; ++it) {
        __syncthreads();   // drains vmcnt: tile `it` resident; prev compute done
        if (it < 31) {
            const int kn = (it + 1) * 64;
            if (cur) STAGE(0, kn) else STAGE(1, kn);
        }

        // ---- QK^T (swapped, pi-permuted A rows): st holds S^T[pi-rows][q=l31]
        f32x16 st0, st1;
#pragma unroll
        for (int i = 0; i < 16; ++i) { st0[i] = 0.f; st1[i] = 0.f; }
        __builtin_amdgcn_s_setprio(1);
#pragma unroll
        for (int dstep = 0; dstep < 4; ++dstep) {
            const int c = dstep * 2 + lhi;
            bf16x8 kf0 = *reinterpret_cast<const bf16x8*>(
                &sK[cur][krow * 64 + ((c ^ ksw) * 8)]);
            bf16x8 kf1 = *reinterpret_cast<const bf16x8*>(
                &sK[cur][(32 + krow) * 64 + ((c ^ ksw) * 8)]);
            st0 = MFMA32(kf0, qf[dstep], st0);
            st1 = MFMA32(kf1, qf[dstep], st1);
        }
        __builtin_amdgcn_s_setprio(0);
        // per-lane k values: st0[i] = S[k], k = (i<8 ? 8*lhi+i : 16+8*lhi+(i-8)); st1: +32.

        // ---- online softmax (lane-local: q = l31; column split across lane, lane^32)
        float m8[8];
#pragma unroll
        for (int j = 0; j < 8; ++j)
            m8[j] = fmaxf(fmaxf(st0[j], st0[j + 8]), fmaxf(st1[j], st1[j + 8]));
        float m4a = fmaxf(m8[0], m8[1]), m4b = fmaxf(m8[2], m8[3]);
        float m4c = fmaxf(m8[4], m8[5]), m4d = fmaxf(m8[6], m8[7]);
        float mx = fmaxf(fmaxf(m4a, m4b), fmaxf(m4c, m4d));
        mx = fmaxf(mx, __shfl_xor(mx, 32));

        if (!__all(mx - mrun <= 8.f)) {      // T13 defer-rescale, THR=8 (P bounded by 2^8)
            const float mnew = fmaxf(mrun, mx);
            const float alpha = __builtin_amdgcn_exp2f(mrun - mnew);
            mrun = mnew;
            lrun *= alpha;
#pragma unroll
            for (int dt = 0; dt < 2; ++dt)
#pragma unroll
                for (int i = 0; i < 16; ++i) acc[dt][i] *= alpha;
        }

#pragma unroll
        for (int i = 0; i < 16; ++i) {
            st0[i] = __builtin_amdgcn_exp2f(st0[i] - mrun);
            st1[i] = __builtin_amdgcn_exp2f(st1[i] - mrun);
        }
        float s8[8];
#pragma unroll
        for (int j = 0; j < 8; ++j)
            s8[j] = (st0[j] + st0[j + 8]) + (st1[j] + st1[j + 8]);
        float sum = ((s8[0] + s8[1]) + (s8[2] + s8[3])) + ((s8[4] + s8[5]) + (s8[6] + s8[7]));
        sum += __shfl_xor(sum, 32);
        lrun += sum;

        // ---- P^T B-fragments: in-register, in-order (thanks to pi) — no cross-lane ops
        bf16x8 pf[4];
#define PACK8(stv, base, out)                                                  \
        {                                                                      \
            u32x4 wv;                                                          \
            wv[0] = pk2(stv[(base) + 0], stv[(base) + 1]);                     \
            wv[1] = pk2(stv[(base) + 2], stv[(base) + 3]);                     \
            wv[2] = pk2(stv[(base) + 4], stv[(base) + 5]);                     \
            wv[3] = pk2(stv[(base) + 6], stv[(base) + 7]);                     \
            out = __builtin_bit_cast(bf16x8, wv);                              \
        }
        PACK8(st0, 0, pf[0])
        PACK8(st0, 8, pf[1])
        PACK8(st1, 0, pf[2])
        PACK8(st1, 8, pf[3])
#undef PACK8

        // ---- PV (swapped): acc[dt] += V^T_tile * P^T, A row d = l31+32dt, contraction k
        __builtin_amdgcn_s_setprio(1);
#pragma unroll
        for (int dt = 0; dt < 2; ++dt) {
            const int rowd = dt * 32 + l31;
#pragma unroll
            for (int ks = 0; ks < 4; ++ks) {
                const int c = ks * 2 + lhi;
                bf16x8 vf = *reinterpret_cast<const bf16x8*>(
                    &sVt[cur][rowd * 64 + ((c ^ vsw) * 8)]);
                acc[dt] = MFMA32(vf, pf[ks], acc[dt]);
            }
        }
        __builtin_amdgcn_s_setprio(0);
        cur ^= 1;
    }

    // ---- epilogue: O[q][d] = acc^T / l;  ctx[b, s=q, h*64+d] bf16
    const float rl = __builtin_amdgcn_rcpf(lrun);
    const int b = hb >> 4, hh = hb & 15;
    const size_t rowbase = ((size_t)(b * 2048 + q0 + l31)) * 1024 + hh * 64;
#pragma unroll
    for (int dt = 0; dt < 2; ++dt) {
#pragma unroll
        for (int rg = 0; rg < 4; ++rg) {
            ushort4 o;
            o.x = f32_to_bf16(acc[dt][4 * rg + 0] * rl);
            o.y = f32_to_bf16(acc[dt][4 * rg + 1] * rl);
            o.z = f32_to_bf16(acc[dt][4 * rg + 2] * rl);
            o.w = f32_to_bf16(acc[dt][4 * rg + 3] * rl);
            const int dbase = dt * 32 + rg * 8 + lhi * 4;
            *reinterpret_cast<ushort4*>(&ctx[rowbase + dbase]) = o;
        }
    }
#undef STAGE
}

// ---------------------------------------------------------------- launch
extern "C" void kernel_launch(void* const* d_in, const int* in_sizes, int n_in,
                              void* d_out, int out_size, void* d_ws, size_t ws_size,
                              hipStream_t stream) {
    const float* x     = (const float*)d_in[0];   // [2,2048,1024]
    const float* w_qkv = (const float*)d_in[1];   // [3072,1024]
    const float* w_out = (const float*)d_in[2];   // [1024,1024]
    float* out = (float*)d_out;                   // [2,2048,1024]

    unsigned short* xb    = (unsigned short*)d_ws;         // 4194304
    unsigned short* wqkvb = xb + 4194304;                  // 3145728
    unsigned short* woutb = wqkvb + 3145728;               // 1048576
    unsigned short* qB    = woutb + 1048576;               // 4194304  [b,h,s,64] (scaled by QSCALE)
    unsigned short* kB    = qB + 4194304;                  // 4194304  [b,h,s,64]
    unsigned short* vB    = kB + 4194304;                  // 4194304  [b,h,d,s] (transposed)
    unsigned short* ctxB  = vB + 4194304;                  // 4194304  [b,s,1024]

    cast3_f32_bf16<<<8192, 256, 0, stream>>>(x, w_qkv, w_out, xb, wqkvb, woutb);

    // QKV: [4096,1024] x [3072,1024]^T
    gemm_bt<0><<<dim3(24, 32), 256, 0, stream>>>(xb, wqkvb, 3072, 1024, qB, kB, vB, nullptr);

    // attention: 32 heads x 16 q-blocks (128 q-rows each)
    attn_kernel<<<512, 256, 0, stream>>>(qB, kB, vB, ctxB);

    // out-proj: [4096,1024] x [1024,1024]^T -> fp32 out
    gemm_bt<1><<<dim3(8, 32), 256, 0, stream>>>(ctxB, woutb, 1024, 1024, nullptr, nullptr, nullptr, out);
}

// Round 7
// 118.675 us; speedup vs baseline: 2.3139x; 1.0512x over previous
//
#include <hip/hip_runtime.h>

typedef __attribute__((ext_vector_type(8))) short bf16x8;
typedef __attribute__((ext_vector_type(4))) float f32x4;
typedef __attribute__((ext_vector_type(16))) float f32x16;
typedef __attribute__((ext_vector_type(4))) unsigned int u32x4;

#define MFMA16(A, B, C) __builtin_amdgcn_mfma_f32_16x16x32_bf16((A), (B), (C), 0, 0, 0)
#define MFMA32(A, B, C) __builtin_amdgcn_mfma_f32_32x32x16_bf16((A), (B), (C), 0, 0, 0)

static __device__ __forceinline__ unsigned short f32_to_bf16(float f) {
    unsigned int u = __builtin_bit_cast(unsigned int, f);
    u += 0x7fffu + ((u >> 16) & 1u);
    return (unsigned short)(u >> 16);
}

// single-instruction pack: dst.lo16 = bf16(lo), dst.hi16 = bf16(hi), RNE (T12 recipe)
static __device__ __forceinline__ unsigned int cvtpk(float lo, float hi) {
    unsigned int r;
    asm("v_cvt_pk_bf16_f32 %0, %1, %2" : "=v"(r) : "v"(lo), "v"(hi));
    return r;
}

// async global->LDS, 16B per lane; LDS dest = wave-uniform base + lane*16
static __device__ __forceinline__ void gload16(const unsigned short* g, unsigned short* l) {
    __builtin_amdgcn_global_load_lds(
        (const __attribute__((address_space(1))) unsigned int*)g,
        (__attribute__((address_space(3))) unsigned int*)l, 16, 0, 0);
}

// fold softmax scale and log2(e) into q so attention uses exp2 directly
#define QSCALE 0.18033688011112042f   // 0.125 * log2(e)

// ---------------------------------------------------------------- fused cast f32 -> bf16 (x, w_qkv, w_out)
__global__ void cast3_f32_bf16(const float* __restrict__ x, const float* __restrict__ wq,
                               const float* __restrict__ wo,
                               unsigned short* __restrict__ xb, unsigned short* __restrict__ wqb,
                               unsigned short* __restrict__ wob) {
    int i = blockIdx.x * 256 + threadIdx.x;   // 2097152 float4 groups total
    const float* src;
    unsigned short* dst;
    int off;
    if (i < 1048576)      { src = x;  dst = xb;  off = i; }
    else if (i < 1835008) { src = wq; dst = wqb; off = i - 1048576; }
    else                  { src = wo; dst = wob; off = i - 1835008; }
    float4 v = reinterpret_cast<const float4*>(src)[off];
    ushort4 o;
    o.x = f32_to_bf16(v.x);
    o.y = f32_to_bf16(v.y);
    o.z = f32_to_bf16(v.z);
    o.w = f32_to_bf16(v.w);
    reinterpret_cast<ushort4*>(dst)[off] = o;
}

// ---------------------------------------------------------------- GEMM  C = A[M,K] * B[N,K]^T
// MODE 0: QKV epilogue (q/k -> [b,h,s,64] bf16, q scaled by QSCALE; V TRANSPOSED -> [b,h,d,s])
// MODE 1: out projection epilogue (fp32 to d_out [M,N])
// Fragment reads span 16 rows/instr -> worst alias is 2-way (free, m136); row&7 key suffices.
template <int MODE>
__global__ __launch_bounds__(256, 2)
void gemm_bt(const unsigned short* __restrict__ Ag,
             const unsigned short* __restrict__ Bg,
             int N, int K,
             unsigned short* __restrict__ qO,
             unsigned short* __restrict__ kO,
             unsigned short* __restrict__ vO,
             float* __restrict__ fO)
{
    constexpr int BM = 128, BN = 128, BK = 64;
    __shared__ unsigned short sA[BM * BK];
    __shared__ unsigned short sB[BN * BK];

    const int m0 = blockIdx.y * BM;
    const int n0 = blockIdx.x * BN;
    const int t = threadIdx.x;
    const int lane = t & 63;
    const int wid = t >> 6;
    const int wr = wid >> 1, wc = wid & 1;   // 2x2 wave grid, 64x64 per wave
    const int g = lane >> 4, r = lane & 15;
    const int lr8 = lane >> 3, lc = lane & 7;

    const f32x4 fzero = {0.f, 0.f, 0.f, 0.f};
    f32x4 acc[4][4];
#pragma unroll
    for (int mi = 0; mi < 4; ++mi)
#pragma unroll
        for (int ni = 0; ni < 4; ++ni) acc[mi][ni] = fzero;

    for (int k0 = 0; k0 < K; k0 += BK) {
        __syncthreads();
        // global_load_lds staging: linear LDS dest, XOR-pre-swizzled global source.
#pragma unroll
        for (int rep = 0; rep < 4; ++rep) {
            const int rbase = rep * 32 + wid * 8;       // wave-uniform
            const int row = rbase + lr8;
            const int cs = lc ^ (row & 7);              // 16B-chunk swizzle
            gload16(&Ag[(size_t)(m0 + row) * K + k0 + cs * 8], &sA[rbase * 64]);
            gload16(&Bg[(size_t)(n0 + row) * K + k0 + cs * 8], &sB[rbase * 64]);
        }
        __syncthreads();

#pragma unroll
        for (int ks = 0; ks < BK; ks += 32) {
            const int c = (ks >> 3) + g;
            bf16x8 af[4], bfr[4];
#pragma unroll
            for (int mi = 0; mi < 4; ++mi) {
                const int row = wr * 64 + mi * 16 + r;
                af[mi] = *reinterpret_cast<const bf16x8*>(&sA[row * BK + ((c * 8) ^ ((row & 7) * 8))]);
            }
#pragma unroll
            for (int ni = 0; ni < 4; ++ni) {
                const int row = wc * 64 + ni * 16 + r;
                bfr[ni] = *reinterpret_cast<const bf16x8*>(&sB[row * BK + ((c * 8) ^ ((row & 7) * 8))]);
            }
#pragma unroll
            for (int mi = 0; mi < 4; ++mi)
#pragma unroll
                for (int ni = 0; ni < 4; ++ni)
                    acc[mi][ni] = MFMA16(af[mi], bfr[ni], acc[mi][ni]);
        }
    }

    // Epilogue. D layout (16x16): row = 4*g + i, col = r.
#pragma unroll
    for (int mi = 0; mi < 4; ++mi) {
#pragma unroll
        for (int ni = 0; ni < 4; ++ni) {
            const int mbase = m0 + wr * 64 + mi * 16 + 4 * g;   // multiple of 4
            const int n = n0 + wc * 64 + ni * 16 + r;
            if (MODE == 0) {
                const int b = mbase >> 11, s = mbase & 2047;    // uniform over i (aligned 4)
                const int which = n >> 10;       // 0=q 1=k 2=v  (uniform per fragment)
                const int h = (n >> 6) & 15;
                const int d = n & 63;
                if (which == 2) {
                    // V transposed: [b,h,d,s]; 4 consecutive s -> packed 8B store
                    ushort4 v4;
                    v4.x = f32_to_bf16(acc[mi][ni][0]);
                    v4.y = f32_to_bf16(acc[mi][ni][1]);
                    v4.z = f32_to_bf16(acc[mi][ni][2]);
                    v4.w = f32_to_bf16(acc[mi][ni][3]);
                    *reinterpret_cast<ushort4*>(&vO[(((size_t)(b * 16 + h)) * 64 + d) * 2048 + s]) = v4;
                } else {
                    const size_t dst = (((size_t)(b * 16 + h)) * 2048 + s) * 64 + d;
#pragma unroll
                    for (int i = 0; i < 4; ++i) {
                        const float val = acc[mi][ni][i];
                        if (which == 0) qO[dst + (size_t)i * 64] = f32_to_bf16(val * QSCALE);
                        else            kO[dst + (size_t)i * 64] = f32_to_bf16(val);
                    }
                }
            } else {
#pragma unroll
                for (int i = 0; i < 4; ++i)
                    fO[(size_t)(mbase + i) * N + n] = acc[mi][ni][i];
            }
        }
    }
}

// ---------------------------------------------------------------- flash attention v3d (32x32 MFMA geometry)
// grid 512 = 32 heads * 16 qblocks (XCD-swizzled). 4 waves * 32 q-rows = 128 q/block. KVBLK=64.
// Swapped QK^T: st[k][q], lane owns q = lane&31 -> softmax lane-local.
// K A-operand rows fed through involution pi(r) = bitswap(r, bits 2<->3) so the lane's 16
// st regs are contiguous in k == PV B-fragment slots (zero cross-lane P ops).
// Swapped PV: acc = O^T[d][q] -> alpha rescale lane-uniform. T13 defer-rescale THR=8.
// LDS swizzle key = (row&7)^((row>>3)&3) -> conflict-free (verified: SQ_LDS_BANK_CONFLICT=0).
// P pack via v_cvt_pk_bf16_f32 (1 instr/pair vs ~10 manual VALU ops).
__global__ __launch_bounds__(256, 2)
void attn_kernel(const unsigned short* __restrict__ Q,
                 const unsigned short* __restrict__ Kg,
                 const unsigned short* __restrict__ Vtg,
                 unsigned short* __restrict__ ctx)
{
    const int S = 2048;
    const int bid = blockIdx.x;
    const int swz = (bid & 7) * 64 + (bid >> 3);   // bijective XCD swizzle (512 % 8 == 0)
    const int hb = swz >> 4;                       // 0..31 = b*16+h
    const int qb = swz & 15;                       // 0..15
    const unsigned short* Qh = Q + (size_t)hb * S * 64;
    const unsigned short* Kh = Kg + (size_t)hb * S * 64;
    const unsigned short* Vh = Vtg + (size_t)hb * 64 * S;   // [d][s]

    const int t = threadIdx.x, lane = t & 63, wid = t >> 6;
    const int l31 = lane & 31, lhi = lane >> 5;
    const int lr8 = lane >> 3, lc = lane & 7;
    const int q0 = qb * 128 + wid * 32;

    // pi(l31): swap bits 2 and 3 (involution)
    const int krow = (l31 & 19) | ((l31 & 4) << 1) | ((l31 & 8) >> 1);
    const int ksw = (krow & 7) ^ ((krow >> 3) & 3);   // valid for rows krow and krow+32
    const int vsw = (l31 & 7) ^ ((l31 >> 3) & 3);     // valid for rows l31 and l31+32

    __shared__ unsigned short sK[2][64 * 64];    // [k][d], 16B-chunk XOR-swizzled
    __shared__ unsigned short sVt[2][64 * 64];   // [d][k], 16B-chunk XOR-swizzled

    // Q B-fragments (col q = l31, contraction d = dstep*16 + lhi*8 + j), in regs all kernel
    bf16x8 qf[4];
#pragma unroll
    for (int dstep = 0; dstep < 4; ++dstep)
        qf[dstep] = *reinterpret_cast<const bf16x8*>(
            &Qh[(size_t)(q0 + l31) * 64 + dstep * 16 + lhi * 8]);

    f32x16 acc[2];   // O^T: acc[dt], row d = 32dt + (reg&3)+8*(reg>>2)+4*lhi, col q = l31
#pragma unroll
    for (int dt = 0; dt < 2; ++dt)
#pragma unroll
        for (int i = 0; i < 16; ++i) acc[dt][i] = 0.f;
    float mrun = -1e30f, lrun = 0.f;

#define STAGE(buf, k0)                                                                   \
    {                                                                                    \
        _Pragma("unroll")                                                                \
        for (int rep = 0; rep < 2; ++rep) {                                              \
            const int rbase = wid * 16 + rep * 8;                                        \
            const int row = rbase + lr8;                                                 \
            const int cs = lc ^ ((row & 7) ^ ((row >> 3) & 3));                          \
            gload16(&Kh[(size_t)((k0) + row) * 64 + cs * 8], &sK[buf][rbase * 64]);      \
            gload16(&Vh[(size_t)row * S + (k0) + cs * 8], &sVt[buf][rbase * 64]);        \
        }                                                                                \
    }

    STAGE(0, 0);
    int cur = 0;

    for (int it = 0; it < 32; ++it) {
        __syncthreads();   // drains vmcnt: tile `it` resident; prev compute done
        if (it < 31) {
            const int kn = (it + 1) * 64;
            if (cur) STAGE(0, kn) else STAGE(1, kn);
        }

        // ---- QK^T (swapped, pi-permuted A rows): st holds S^T[pi-rows][q=l31]
        f32x16 st0, st1;
#pragma unroll
        for (int i = 0; i < 16; ++i) { st0[i] = 0.f; st1[i] = 0.f; }
        __builtin_amdgcn_s_setprio(1);
#pragma unroll
        for (int dstep = 0; dstep < 4; ++dstep) {
            const int c = dstep * 2 + lhi;
            bf16x8 kf0 = *reinterpret_cast<const bf16x8*>(
                &sK[cur][krow * 64 + ((c ^ ksw) * 8)]);
            bf16x8 kf1 = *reinterpret_cast<const bf16x8*>(
                &sK[cur][(32 + krow) * 64 + ((c ^ ksw) * 8)]);
            st0 = MFMA32(kf0, qf[dstep], st0);
            st1 = MFMA32(kf1, qf[dstep], st1);
        }
        __builtin_amdgcn_s_setprio(0);
        // per-lane k values: st0[i] = S[k], k = (i<8 ? 8*lhi+i : 16+8*lhi+(i-8)); st1: +32.

        // ---- online softmax (lane-local: q = l31; column split across lane, lane^32)
        float m8[8];
#pragma unroll
        for (int j = 0; j < 8; ++j)
            m8[j] = fmaxf(fmaxf(st0[j], st0[j + 8]), fmaxf(st1[j], st1[j + 8]));
        float m4a = fmaxf(m8[0], m8[1]), m4b = fmaxf(m8[2], m8[3]);
        float m4c = fmaxf(m8[4], m8[5]), m4d = fmaxf(m8[6], m8[7]);
        float mx = fmaxf(fmaxf(m4a, m4b), fmaxf(m4c, m4d));
        mx = fmaxf(mx, __shfl_xor(mx, 32));

        if (!__all(mx - mrun <= 8.f)) {      // T13 defer-rescale, THR=8 (P bounded by 2^8)
            const float mnew = fmaxf(mrun, mx);
            const float alpha = __builtin_amdgcn_exp2f(mrun - mnew);
            mrun = mnew;
            lrun *= alpha;
#pragma unroll
            for (int dt = 0; dt < 2; ++dt)
#pragma unroll
                for (int i = 0; i < 16; ++i) acc[dt][i] *= alpha;
        }

#pragma unroll
        for (int i = 0; i < 16; ++i) {
            st0[i] = __builtin_amdgcn_exp2f(st0[i] - mrun);
            st1[i] = __builtin_amdgcn_exp2f(st1[i] - mrun);
        }
        float s8[8];
#pragma unroll
        for (int j = 0; j < 8; ++j)
            s8[j] = (st0[j] + st0[j + 8]) + (st1[j] + st1[j + 8]);
        float sum = ((s8[0] + s8[1]) + (s8[2] + s8[3])) + ((s8[4] + s8[5]) + (s8[6] + s8[7]));
        sum += __shfl_xor(sum, 32);
        lrun += sum;

        // ---- P^T B-fragments: in-register, in-order (thanks to pi), 1 cvt_pk per pair
        bf16x8 pf[4];
#define PACK8(stv, base, out)                                                  \
        {                                                                      \
            u32x4 wv;                                                          \
            wv[0] = cvtpk(stv[(base) + 0], stv[(base) + 1]);                   \
            wv[1] = cvtpk(stv[(base) + 2], stv[(base) + 3]);                   \
            wv[2] = cvtpk(stv[(base) + 4], stv[(base) + 5]);                   \
            wv[3] = cvtpk(stv[(base) + 6], stv[(base) + 7]);                   \
            out = __builtin_bit_cast(bf16x8, wv);                              \
        }
        PACK8(st0, 0, pf[0])
        PACK8(st0, 8, pf[1])
        PACK8(st1, 0, pf[2])
        PACK8(st1, 8, pf[3])
#undef PACK8

        // ---- PV (swapped): acc[dt] += V^T_tile * P^T, A row d = l31+32dt, contraction k
        __builtin_amdgcn_s_setprio(1);
#pragma unroll
        for (int dt = 0; dt < 2; ++dt) {
            const int rowd = dt * 32 + l31;
#pragma unroll
            for (int ks = 0; ks < 4; ++ks) {
                const int c = ks * 2 + lhi;
                bf16x8 vf = *reinterpret_cast<const bf16x8*>(
                    &sVt[cur][rowd * 64 + ((c ^ vsw) * 8)]);
                acc[dt] = MFMA32(vf, pf[ks], acc[dt]);
            }
        }
        __builtin_amdgcn_s_setprio(0);
        cur ^= 1;
    }

    // ---- epilogue: O[q][d] = acc^T / l;  ctx[b, s=q, h*64+d] bf16
    const float rl = __builtin_amdgcn_rcpf(lrun);
    const int b = hb >> 4, hh = hb & 15;
    const size_t rowbase = ((size_t)(b * 2048 + q0 + l31)) * 1024 + hh * 64;
#pragma unroll
    for (int dt = 0; dt < 2; ++dt) {
#pragma unroll
        for (int rg = 0; rg < 4; ++rg) {
            uint2 o;
            o.x = cvtpk(acc[dt][4 * rg + 0] * rl, acc[dt][4 * rg + 1] * rl);
            o.y = cvtpk(acc[dt][4 * rg + 2] * rl, acc[dt][4 * rg + 3] * rl);
            const int dbase = dt * 32 + rg * 8 + lhi * 4;
            *reinterpret_cast<uint2*>(&ctx[rowbase + dbase]) = o;
        }
    }
#undef STAGE
}

// ---------------------------------------------------------------- launch
extern "C" void kernel_launch(void* const* d_in, const int* in_sizes, int n_in,
                              void* d_out, int out_size, void* d_ws, size_t ws_size,
                              hipStream_t stream) {
    const float* x     = (const float*)d_in[0];   // [2,2048,1024]
    const float* w_qkv = (const float*)d_in[1];   // [3072,1024]
    const float* w_out = (const float*)d_in[2];   // [1024,1024]
    float* out = (float*)d_out;                   // [2,2048,1024]

    unsigned short* xb    = (unsigned short*)d_ws;         // 4194304
    unsigned short* wqkvb = xb + 4194304;                  // 3145728
    unsigned short* woutb = wqkvb + 3145728;               // 1048576
    unsigned short* qB    = woutb + 1048576;               // 4194304  [b,h,s,64] (scaled by QSCALE)
    unsigned short* kB    = qB + 4194304;                  // 4194304  [b,h,s,64]
    unsigned short* vB    = kB + 4194304;                  // 4194304  [b,h,d,s] (transposed)
    unsigned short* ctxB  = vB + 4194304;                  // 4194304  [b,s,1024]

    cast3_f32_bf16<<<8192, 256, 0, stream>>>(x, w_qkv, w_out, xb, wqkvb, woutb);

    // QKV: [4096,1024] x [3072,1024]^T
    gemm_bt<0><<<dim3(24, 32), 256, 0, stream>>>(xb, wqkvb, 3072, 1024, qB, kB, vB, nullptr);

    // attention: 32 heads x 16 q-blocks (128 q-rows each)
    attn_kernel<<<512, 256, 0, stream>>>(qB, kB, vB, ctxB);

    // out-proj: [4096,1024] x [1024,1024]^T -> fp32 out
    gemm_bt<1><<<dim3(8, 32), 256, 0, stream>>>(ctxB, woutb, 1024, 1024, nullptr, nullptr, nullptr, out);
}